// Round 2
// baseline (1405.090 us; speedup 1.0000x reference)
//
#include <hip/hip_runtime.h>
#include <hip/hip_bf16.h>

typedef short s16x8 __attribute__((ext_vector_type(8)));
typedef float f32x4 __attribute__((ext_vector_type(4)));

#define NTOK 16384           // H*W per batch
#define MROWS 65536          // b * NTOK

__device__ __forceinline__ float bf2f(unsigned short u) {
  union { unsigned int i; float f; } v; v.i = ((unsigned int)u) << 16; return v.f;
}
__device__ __forceinline__ unsigned short f2bf(float f) {
  union { float f; unsigned int i; } v; v.f = f;
  unsigned int x = v.i;
  return (unsigned short)((x + 0x7fffu + ((x >> 16) & 1u)) >> 16);
}

// ---------------------------------------------------------------------------
// Transpose+convert a 512x512 fp32 weight to bf16: Wt[n][k] = W[k][n]
__global__ void transpose512(const float* __restrict__ W,
                             unsigned short* __restrict__ Wt) {
  int idx = blockIdx.x * 256 + threadIdx.x;   // = n*512 + k
  int n = idx >> 9, k = idx & 511;
  Wt[idx] = f2bf(W[k * 512 + n]);
}

// ---------------------------------------------------------------------------
__device__ __forceinline__ s16x8 load8(const unsigned short* p) {
  return *(const s16x8*)p;
}
__device__ __forceinline__ s16x8 load8(const float* p) {
  float4 f0 = *(const float4*)p;
  float4 f1 = *(const float4*)(p + 4);
  s16x8 r;
  r[0] = (short)f2bf(f0.x); r[1] = (short)f2bf(f0.y);
  r[2] = (short)f2bf(f0.z); r[3] = (short)f2bf(f0.w);
  r[4] = (short)f2bf(f1.x); r[5] = (short)f2bf(f1.y);
  r[6] = (short)f2bf(f1.z); r[7] = (short)f2bf(f1.w);
  return r;
}
__device__ __forceinline__ void storeC(unsigned short* p, float v) { *p = f2bf(v); }
__device__ __forceinline__ void storeC(float* p, float v) { *p = v; }

// C[M,512] = A[M,512] @ Bt[512,512]^T  (internal bf16 MFMA; fp32 accumulate)
// MODE 0: plain store. MODE 1: += bp[n] + outp[m,n] (final fused output).
// Block: 256 thr = 4 waves (2x2), 128x128 tile, BK=32, 16x16x32 bf16 MFMA.
template <int MODE, typename AT, typename CT>
__global__ __launch_bounds__(256)
void gemm_bt(const AT* __restrict__ A,
             const unsigned short* __restrict__ Bt,
             CT* __restrict__ C,
             const float* __restrict__ bp,
             const unsigned short* __restrict__ outp) {
  __shared__ short sA[128 * 32];
  __shared__ short sB[128 * 32];
  const int tid = threadIdx.x;
  const int m0 = blockIdx.x * 128;
  const int n0 = blockIdx.y * 128;
  const int w = tid >> 6;
  const int lane = tid & 63;
  const int wr = (w >> 1) * 64;   // wave row offset in tile
  const int wc = (w & 1) * 64;    // wave col offset in tile
  const int lrow = lane & 15;
  const int quad = lane >> 4;

  f32x4 acc[4][4];
#pragma unroll
  for (int i = 0; i < 4; ++i)
#pragma unroll
    for (int j = 0; j < 4; ++j) acc[i][j] = (f32x4)(0.0f);

  const int r = tid >> 2;          // 0..63
  const int c8 = (tid & 3) * 8;    // 0,8,16,24

  for (int k0 = 0; k0 < 512; k0 += 32) {
    __syncthreads();
#pragma unroll
    for (int rep = 0; rep < 2; ++rep) {
      int rr = r + rep * 64;
      *(s16x8*)&sA[rr * 32 + c8] = load8(&A[(size_t)(m0 + rr) * 512 + k0 + c8]);
      *(s16x8*)&sB[rr * 32 + c8] = load8(&Bt[(size_t)(n0 + rr) * 512 + k0 + c8]);
    }
    __syncthreads();
    s16x8 af[4], bfr[4];
#pragma unroll
    for (int i = 0; i < 4; ++i)
      af[i] = *(s16x8*)&sA[(wr + i * 16 + lrow) * 32 + quad * 8];
#pragma unroll
    for (int j = 0; j < 4; ++j)
      bfr[j] = *(s16x8*)&sB[(wc + j * 16 + lrow) * 32 + quad * 8];
#pragma unroll
    for (int i = 0; i < 4; ++i)
#pragma unroll
      for (int j = 0; j < 4; ++j)
        acc[i][j] = __builtin_amdgcn_mfma_f32_16x16x32_bf16(af[i], bfr[j],
                                                            acc[i][j], 0, 0, 0);
  }

#pragma unroll
  for (int i = 0; i < 4; ++i)
#pragma unroll
    for (int j = 0; j < 4; ++j)
#pragma unroll
      for (int rg = 0; rg < 4; ++rg) {
        int row = wr + i * 16 + quad * 4 + rg;   // C/D: row=(lane>>4)*4+reg
        int col = wc + j * 16 + lrow;            //      col=lane&15
        size_t m = (size_t)(m0 + row);
        int n = n0 + col;
        float v = acc[i][j][rg];
        if (MODE == 1) v += bp[n] + bf2f(outp[m * 512 + n]);
        storeC(&C[m * 512 + n], v);
      }
}

// ---------------------------------------------------------------------------
// sumsq over token dim per (tensor,b,c). out layout [2][4][512] fp32 (zeroed).
__global__ __launch_bounds__(256)
void sumsq_kernel(const unsigned short* __restrict__ q,
                  const unsigned short* __restrict__ k,
                  float* __restrict__ out) {
  const unsigned short* src = blockIdx.z ? k : q;
  float* dst = out + (size_t)blockIdx.z * 2048;
  int b = blockIdx.y;
  int n0 = blockIdx.x * 1024;
  int t = threadIdx.x;
  float a0 = 0.f, a1 = 0.f;
  const unsigned short* base = src + ((size_t)b * NTOK + n0) * 512;
  for (int n = 0; n < 1024; ++n) {
    float x0 = bf2f(base[(size_t)n * 512 + t]);
    float x1 = bf2f(base[(size_t)n * 512 + t + 256]);
    a0 += x0 * x0;
    a1 += x1 * x1;
  }
  atomicAdd(&dst[b * 512 + t], a0);
  atomicAdd(&dst[b * 512 + t + 256], a1);
}

__global__ void inv_norm_kernel(float* s) {
  int i = blockIdx.x * 256 + threadIdx.x;   // 4096 total
  s[i] = 1.f / fmaxf(sqrtf(s[i]), 1e-12f);
}

// ---------------------------------------------------------------------------
// S[b,h,d,e] += sum_{n-chunk} k[b,n,h*64+d] * q[b,n,h*64+e]   (fp32 atomics)
__global__ __launch_bounds__(256)
void score_kernel(const unsigned short* __restrict__ q,
                  const unsigned short* __restrict__ k,
                  float* __restrict__ S) {
  int bh = blockIdx.x, b = bh >> 3, h = bh & 7;
  int n0 = blockIdx.y * 512;
  __shared__ float sK[16 * 64], sQ[16 * 64];
  int tid = threadIdx.x;
  int ty = tid >> 4, tx = tid & 15;
  float acc[4][4] = {};
  size_t base = ((size_t)b * NTOK + n0) * 512 + h * 64;
  const int srr = tid >> 4;          // staging row (tid*4)>>6
  const int scc = (tid * 4) & 63;    // staging col
  for (int nt = 0; nt < 512; nt += 16) {
    __syncthreads();
    {
      size_t g = base + (size_t)(nt + srr) * 512 + scc;
      ushort4 uk = *(const ushort4*)&k[g];
      ushort4 uq = *(const ushort4*)&q[g];
      *(float4*)&sK[tid * 4] =
          make_float4(bf2f(uk.x), bf2f(uk.y), bf2f(uk.z), bf2f(uk.w));
      *(float4*)&sQ[tid * 4] =
          make_float4(bf2f(uq.x), bf2f(uq.y), bf2f(uq.z), bf2f(uq.w));
    }
    __syncthreads();
#pragma unroll
    for (int nn = 0; nn < 16; ++nn) {
      float4 kv = *(float4*)&sK[nn * 64 + ty * 4];
      float4 qv = *(float4*)&sQ[nn * 64 + tx * 4];
      float kr[4] = {kv.x, kv.y, kv.z, kv.w};
      float qr[4] = {qv.x, qv.y, qv.z, qv.w};
#pragma unroll
      for (int rr = 0; rr < 4; ++rr)
#pragma unroll
        for (int cc = 0; cc < 4; ++cc) acc[rr][cc] += kr[rr] * qr[cc];
    }
  }
  float* Sp = S + (size_t)bh * 64 * 64;
#pragma unroll
  for (int rr = 0; rr < 4; ++rr)
#pragma unroll
    for (int cc = 0; cc < 4; ++cc)
      atomicAdd(&Sp[(ty * 4 + rr) * 64 + tx * 4 + cc], acc[rr][cc]);
}

// ---------------------------------------------------------------------------
// softmax over e with normalization scales folded in. One wave per (b,h,d).
__global__ void softmax_kernel(float* __restrict__ S,
                               const float* __restrict__ inv,
                               const float* __restrict__ rescale) {
  int row = blockIdx.x;            // bh*64 + d
  int bh = row >> 6, d = row & 63;
  int b = bh >> 3, h = bh & 7;
  int e = threadIdx.x;
  const float* invq = inv;         // [4][512]
  const float* invk = inv + 2048;
  float v = S[(size_t)row * 64 + e] * invk[b * 512 + h * 64 + d] *
            invq[b * 512 + h * 64 + e] * rescale[h];
  float m = v;
#pragma unroll
  for (int off = 32; off; off >>= 1) m = fmaxf(m, __shfl_xor(m, off));
  float ex = expf(v - m);
  float s = ex;
#pragma unroll
  for (int off = 32; off; off >>= 1) s += __shfl_xor(s, off);
  S[(size_t)row * 64 + e] = ex / s;
}

// ---------------------------------------------------------------------------
// xo[b,t,c=h*64+d] = sum_e attn[b,h,d,e] * (v_inp*illu)[b,t,h*64+e]
// Wave w handles head h=w: all lanes share h, so use shfl broadcast (no LDS).
__global__ __launch_bounds__(512)
void xo_kernel(const unsigned short* __restrict__ v_inp,
               const float* __restrict__ illu,
               const float* __restrict__ attn,
               unsigned short* __restrict__ xo) {
  int b = blockIdx.x;
  int t0 = blockIdx.y * 256;
  int c = threadIdx.x;
  int h = c >> 6;
  float arow[64];
  const float* ap = attn + ((size_t)(b * 8 + h) * 64 + (c & 63)) * 64;
#pragma unroll
  for (int e = 0; e < 64; ++e) arow[e] = ap[e];
  for (int t = t0; t < t0 + 256; ++t) {
    size_t g = ((size_t)b * NTOK + t) * 512 + c;
    float vv = bf2f(v_inp[g]) * illu[g];
    float a = 0.f;
#pragma unroll
    for (int e = 0; e < 64; ++e) a += arow[e] * __shfl(vv, e);
    xo[g] = f2bf(a);
  }
}

// ---------------------------------------------------------------------------
// depthwise 3x3, SAME pad, NHWC (b,128,128,512). 2 channels/thread.
__global__ __launch_bounds__(256)
void dwconv_kernel(const unsigned short* __restrict__ in,
                   const float* __restrict__ w,
                   unsigned short* __restrict__ out, int do_gelu) {
  size_t i = (size_t)blockIdx.x * 256 + threadIdx.x;  // pair index
  int c2 = (int)(i & 255);
  int c = c2 * 2;
  size_t p = i >> 8;
  int x = (int)(p & 127);
  int y = (int)((p >> 7) & 127);
  int b = (int)(p >> 14);
  float w0[9], w1[9];
#pragma unroll
  for (int kk = 0; kk < 9; ++kk) { w0[kk] = w[c * 9 + kk]; w1[kk] = w[c * 9 + 9 + kk]; }
  float a0 = 0.f, a1 = 0.f;
#pragma unroll
  for (int ky = 0; ky < 3; ++ky) {
    int yy = y + ky - 1;
    if (yy < 0 || yy > 127) continue;
#pragma unroll
    for (int kx = 0; kx < 3; ++kx) {
      int xx = x + kx - 1;
      if (xx < 0 || xx > 127) continue;
      size_t g = ((((size_t)b * 128 + yy) * 128 + xx) << 9) + c;
      ushort2 u = *(const ushort2*)&in[g];
      a0 += w0[ky * 3 + kx] * bf2f(u.x);
      a1 += w1[ky * 3 + kx] * bf2f(u.y);
    }
  }
  if (do_gelu) {
    a0 = 0.5f * a0 * (1.f + erff(a0 * 0.70710678118654752f));
    a1 = 0.5f * a1 * (1.f + erff(a1 * 0.70710678118654752f));
  }
  unsigned short r[2] = {f2bf(a0), f2bf(a1)};
  *(ushort2*)&out[i * 2] = *(ushort2*)r;
}

// ---------------------------------------------------------------------------
extern "C" void kernel_launch(void* const* d_in, const int* in_sizes, int n_in,
                              void* d_out, int out_size, void* d_ws,
                              size_t ws_size, hipStream_t stream) {
  const float* x    = (const float*)d_in[0];
  const float* illu = (const float*)d_in[1];
  const float* Wq   = (const float*)d_in[2];
  const float* Wk   = (const float*)d_in[3];
  const float* Wv   = (const float*)d_in[4];
  const float* resc = (const float*)d_in[5];
  const float* Wp   = (const float*)d_in[6];
  const float* bp   = (const float*)d_in[7];
  const float* c1w  = (const float*)d_in[8];
  const float* c2w  = (const float*)d_in[9];
  float* out = (float*)d_out;

  char* ws = (char*)d_ws;
  const size_t SZ = (size_t)MROWS * 512 * sizeof(unsigned short);  // 64 MiB
  unsigned short* q_ws  = (unsigned short*)(ws);           // later: conv tmp
  unsigned short* k_ws  = (unsigned short*)(ws + SZ);      // later: out_p
  unsigned short* v_ws  = (unsigned short*)(ws + 2 * SZ);
  unsigned short* xo_ws = (unsigned short*)(ws + 3 * SZ);
  unsigned short* WqT = (unsigned short*)(ws + 4 * SZ);
  unsigned short* WkT = WqT + 512 * 512;
  unsigned short* WvT = WkT + 512 * 512;
  unsigned short* WpT = WvT + 512 * 512;
  float* S   = (float*)(WpT + 512 * 512);   // [4][8][64][64]
  float* inv = S + 4 * 8 * 64 * 64;         // [2][4][512]

  transpose512<<<1024, 256, 0, stream>>>(Wq, WqT);
  transpose512<<<1024, 256, 0, stream>>>(Wk, WkT);
  transpose512<<<1024, 256, 0, stream>>>(Wv, WvT);
  transpose512<<<1024, 256, 0, stream>>>(Wp, WpT);
  hipMemsetAsync(S, 0, (size_t)(4 * 8 * 64 * 64 + 2 * 4 * 512) * sizeof(float),
                 stream);

  // projections (fp32 in -> bf16 out)
  gemm_bt<0, float, unsigned short>
      <<<dim3(512, 4), 256, 0, stream>>>(x, WqT, q_ws, nullptr, nullptr);
  gemm_bt<0, float, unsigned short>
      <<<dim3(512, 4), 256, 0, stream>>>(x, WkT, k_ws, nullptr, nullptr);
  gemm_bt<0, float, unsigned short>
      <<<dim3(512, 4), 256, 0, stream>>>(x, WvT, v_ws, nullptr, nullptr);

  // norms + attention scores + softmax
  sumsq_kernel<<<dim3(16, 4, 2), 256, 0, stream>>>(q_ws, k_ws, inv);
  inv_norm_kernel<<<16, 256, 0, stream>>>(inv);
  score_kernel<<<dim3(32, 32), 256, 0, stream>>>(q_ws, k_ws, S);
  softmax_kernel<<<2048, 64, 0, stream>>>(S, inv, resc);

  // positional branch (q_ws/k_ws free after score_kernel)
  dwconv_kernel<<<65536, 256, 0, stream>>>(v_ws, c1w, q_ws, 1);
  dwconv_kernel<<<65536, 256, 0, stream>>>(q_ws, c2w, k_ws, 0);

  // attn @ v (illumination gating fused)
  xo_kernel<<<dim3(4, 64), 512, 0, stream>>>(v_ws, illu, S, xo_ws);

  // output projection + bias + positional branch, write fp32 output
  gemm_bt<1, unsigned short, float>
      <<<dim3(512, 4), 256, 0, stream>>>(xo_ws, WpT, out, bp, k_ws);
}

// Round 3
// 956.849 us; speedup vs baseline: 1.4685x; 1.4685x over previous
//
#include <hip/hip_runtime.h>
#include <hip/hip_bf16.h>

typedef short s16x8 __attribute__((ext_vector_type(8)));
typedef float f32x4 __attribute__((ext_vector_type(4)));

#define NTOK 16384           // H*W per batch
#define MROWS 65536          // b * NTOK

__device__ __forceinline__ float bf2f(unsigned short u) {
  union { unsigned int i; float f; } v; v.i = ((unsigned int)u) << 16; return v.f;
}
__device__ __forceinline__ unsigned short f2bf(float f) {
  union { float f; unsigned int i; } v; v.f = f;
  unsigned int x = v.i;
  return (unsigned short)((x + 0x7fffu + ((x >> 16) & 1u)) >> 16);
}

// async global->LDS, 16B per lane. LDS dest must be wave-uniform base + lane*16.
__device__ __forceinline__ void async16(const unsigned short* g, short* l) {
  __builtin_amdgcn_global_load_lds(
      (__attribute__((address_space(1))) void*)(unsigned short*)g,
      (__attribute__((address_space(3))) void*)l, 16, 0, 0);
}

// ---------------------------------------------------------------------------
// Transpose+convert a 512x512 fp32 weight to bf16: Wt[n][k] = W[k][n]
__global__ void transpose512(const float* __restrict__ W,
                             unsigned short* __restrict__ Wt) {
  int idx = blockIdx.x * 256 + threadIdx.x;   // = n*512 + k
  int n = idx >> 9, k = idx & 511;
  Wt[idx] = f2bf(W[k * 512 + n]);
}

// fp32 -> bf16 bulk convert (4 elems/thread)
__global__ void convert_bf16(const float* __restrict__ in,
                             unsigned short* __restrict__ out) {
  size_t i = ((size_t)blockIdx.x * 256 + threadIdx.x) * 4;
  float4 f = *(const float4*)&in[i];
  unsigned short u[4] = {f2bf(f.x), f2bf(f.y), f2bf(f.z), f2bf(f.w)};
  *(ushort4*)&out[i] = *(ushort4*)u;
}

// vg = v * illu (4 elems/thread)
__global__ void gate_kernel(const unsigned short* __restrict__ v,
                            const float* __restrict__ illu,
                            unsigned short* __restrict__ vg) {
  size_t i = ((size_t)blockIdx.x * 256 + threadIdx.x) * 4;
  ushort4 uv = *(const ushort4*)&v[i];
  float4 f = *(const float4*)&illu[i];
  unsigned short u[4] = {f2bf(bf2f(uv.x) * f.x), f2bf(bf2f(uv.y) * f.y),
                         f2bf(bf2f(uv.z) * f.z), f2bf(bf2f(uv.w) * f.w)};
  *(ushort4*)&vg[i] = *(ushort4*)u;
}

// ---------------------------------------------------------------------------
// C[M,512] = A[M,512] @ Bt[512,512]^T  (bf16 MFMA; fp32 accumulate)
// MODE 0: store bf16. MODE 1: batched Bt (per 16384 rows), += bp[n]+outp[m,n],
// store fp32 (final output). Block: 256 thr = 4 waves (2x2), 128x128 tile,
// BK=32, 16x16x32 bf16 MFMA, global_load_lds width-16 staging.
template <int MODE>
__global__ __launch_bounds__(256)
void gemm_bt(const unsigned short* __restrict__ A,
             const unsigned short* __restrict__ Bt,
             void* __restrict__ Cv,
             const float* __restrict__ bp,
             const unsigned short* __restrict__ outp) {
  __shared__ short sA[128 * 32];
  __shared__ short sB[128 * 32];
  const int tid = threadIdx.x;
  const int m0 = blockIdx.x * 128;
  const int n0 = blockIdx.y * 128;
  if (MODE == 1) Bt += (size_t)(m0 >> 14) * (512 * 512);  // per-batch B
  const int w = tid >> 6;
  const int lane = tid & 63;
  const int wr = (w >> 1) * 64;   // wave row offset in tile
  const int wc = (w & 1) * 64;    // wave col offset in tile
  const int lrow = lane & 15;
  const int quad = lane >> 4;

  f32x4 acc[4][4];
#pragma unroll
  for (int i = 0; i < 4; ++i)
#pragma unroll
    for (int j = 0; j < 4; ++j) acc[i][j] = (f32x4)(0.0f);

  const int r = tid >> 2;          // 0..63
  const int c8 = (tid & 3) * 8;    // 0,8,16,24 (shorts)
  const unsigned short* Ar0 = A + (size_t)(m0 + r) * 512 + c8;
  const unsigned short* Ar1 = Ar0 + (size_t)64 * 512;
  const unsigned short* Br0 = Bt + (size_t)(n0 + r) * 512 + c8;
  const unsigned short* Br1 = Br0 + (size_t)64 * 512;
  short* sAp = &sA[tid * 8];       // == (r*32 + c8), lane-contiguous 16B
  short* sBp = &sB[tid * 8];

  for (int k0 = 0; k0 < 512; k0 += 32) {
    __syncthreads();
    async16(Ar0 + k0, sAp);
    async16(Ar1 + k0, sAp + 64 * 32);
    async16(Br0 + k0, sBp);
    async16(Br1 + k0, sBp + 64 * 32);
    __syncthreads();
    s16x8 af[4], bfr[4];
#pragma unroll
    for (int i = 0; i < 4; ++i)
      af[i] = *(s16x8*)&sA[(wr + i * 16 + lrow) * 32 + quad * 8];
#pragma unroll
    for (int j = 0; j < 4; ++j)
      bfr[j] = *(s16x8*)&sB[(wc + j * 16 + lrow) * 32 + quad * 8];
#pragma unroll
    for (int i = 0; i < 4; ++i)
#pragma unroll
      for (int j = 0; j < 4; ++j)
        acc[i][j] = __builtin_amdgcn_mfma_f32_16x16x32_bf16(af[i], bfr[j],
                                                            acc[i][j], 0, 0, 0);
  }

#pragma unroll
  for (int i = 0; i < 4; ++i)
#pragma unroll
    for (int j = 0; j < 4; ++j)
#pragma unroll
      for (int rg = 0; rg < 4; ++rg) {
        int row = wr + i * 16 + quad * 4 + rg;   // C/D: row=(lane>>4)*4+reg
        int col = wc + j * 16 + lrow;            //      col=lane&15
        size_t m = (size_t)(m0 + row);
        int n = n0 + col;
        float v = acc[i][j][rg];
        if (MODE == 1) {
          ((float*)Cv)[m * 512 + n] = v + bp[n] + bf2f(outp[m * 512 + n]);
        } else {
          ((unsigned short*)Cv)[m * 512 + n] = f2bf(v);
        }
      }
}

// ---------------------------------------------------------------------------
// sumsq over token dim per (tensor,b,c). out layout [2][4][512] fp32 (zeroed).
__global__ __launch_bounds__(256)
void sumsq_kernel(const unsigned short* __restrict__ q,
                  const unsigned short* __restrict__ k,
                  float* __restrict__ out) {
  const unsigned short* src = blockIdx.z ? k : q;
  float* dst = out + (size_t)blockIdx.z * 2048;
  int b = blockIdx.y;
  int n0 = blockIdx.x * 256;
  int t = threadIdx.x;
  float a0 = 0.f, a1 = 0.f;
  const unsigned short* base = src + ((size_t)b * NTOK + n0) * 512;
  for (int n = 0; n < 256; ++n) {
    float x0 = bf2f(base[(size_t)n * 512 + t]);
    float x1 = bf2f(base[(size_t)n * 512 + t + 256]);
    a0 += x0 * x0;
    a1 += x1 * x1;
  }
  atomicAdd(&dst[b * 512 + t], a0);
  atomicAdd(&dst[b * 512 + t + 256], a1);
}

__global__ void inv_norm_kernel(float* s) {
  int i = blockIdx.x * 256 + threadIdx.x;   // 4096 total
  s[i] = 1.f / fmaxf(sqrtf(s[i]), 1e-12f);
}

// ---------------------------------------------------------------------------
// S[b,h,d,e] += sum_{n-chunk} k[b,n,h*64+d] * q[b,n,h*64+e]   (fp32 atomics)
__global__ __launch_bounds__(256)
void score_kernel(const unsigned short* __restrict__ q,
                  const unsigned short* __restrict__ k,
                  float* __restrict__ S) {
  int bh = blockIdx.x, b = bh >> 3, h = bh & 7;
  int n0 = blockIdx.y * 512;
  __shared__ float sK[16 * 64], sQ[16 * 64];
  int tid = threadIdx.x;
  int ty = tid >> 4, tx = tid & 15;
  float acc[4][4] = {};
  size_t base = ((size_t)b * NTOK + n0) * 512 + h * 64;
  const int srr = tid >> 4;          // staging row
  const int scc = (tid * 4) & 63;    // staging col
  for (int nt = 0; nt < 512; nt += 16) {
    __syncthreads();
    {
      size_t g = base + (size_t)(nt + srr) * 512 + scc;
      ushort4 uk = *(const ushort4*)&k[g];
      ushort4 uq = *(const ushort4*)&q[g];
      *(float4*)&sK[tid * 4] =
          make_float4(bf2f(uk.x), bf2f(uk.y), bf2f(uk.z), bf2f(uk.w));
      *(float4*)&sQ[tid * 4] =
          make_float4(bf2f(uq.x), bf2f(uq.y), bf2f(uq.z), bf2f(uq.w));
    }
    __syncthreads();
#pragma unroll
    for (int nn = 0; nn < 16; ++nn) {
      float4 kv = *(float4*)&sK[nn * 64 + ty * 4];
      float4 qv = *(float4*)&sQ[nn * 64 + tx * 4];
      float kr[4] = {kv.x, kv.y, kv.z, kv.w};
      float qr[4] = {qv.x, qv.y, qv.z, qv.w};
#pragma unroll
      for (int rr = 0; rr < 4; ++rr)
#pragma unroll
        for (int cc = 0; cc < 4; ++cc) acc[rr][cc] += kr[rr] * qr[cc];
    }
  }
  float* Sp = S + (size_t)bh * 64 * 64;
#pragma unroll
  for (int rr = 0; rr < 4; ++rr)
#pragma unroll
    for (int cc = 0; cc < 4; ++cc)
      atomicAdd(&Sp[(ty * 4 + rr) * 64 + tx * 4 + cc], acc[rr][cc]);
}

// ---------------------------------------------------------------------------
// softmax over e with normalization scales folded in. One wave per (b,h,d).
__global__ void softmax_kernel(float* __restrict__ S,
                               const float* __restrict__ inv,
                               const float* __restrict__ rescale) {
  int row = blockIdx.x;            // bh*64 + d
  int bh = row >> 6, d = row & 63;
  int b = bh >> 3, h = bh & 7;
  int e = threadIdx.x;
  const float* invq = inv;         // [4][512]
  const float* invk = inv + 2048;
  float v = S[(size_t)row * 64 + e] * invk[b * 512 + h * 64 + d] *
            invq[b * 512 + h * 64 + e] * rescale[h];
  float m = v;
#pragma unroll
  for (int off = 32; off; off >>= 1) m = fmaxf(m, __shfl_xor(m, off));
  float ex = expf(v - m);
  float s = ex;
#pragma unroll
  for (int off = 32; off; off >>= 1) s += __shfl_xor(s, off);
  S[(size_t)row * 64 + e] = ex / s;
}

// ---------------------------------------------------------------------------
// M2T[b][n][h*64+e] = sum_d attn[b,h,d,e] * WpT[n][h*64+d]  (bf16 out)
// Folds attention into the output projection: out_c = Vg @ M2T^T.
__global__ __launch_bounds__(256)
void combine_kernel(const float* __restrict__ S,
                    const unsigned short* __restrict__ WpT,
                    unsigned short* __restrict__ M2T) {
  int bn = blockIdx.x;
  int b = bn >> 9, n = bn & 511;
  int tid = threadIdx.x;
  __shared__ float sW[512];
  sW[tid] = bf2f(WpT[n * 512 + tid]);
  sW[tid + 256] = bf2f(WpT[n * 512 + tid + 256]);
  __syncthreads();
#pragma unroll
  for (int cc = 0; cc < 2; ++cc) {
    int c = tid + cc * 256;
    int h = c >> 6, e = c & 63;
    const float* ap = S + ((size_t)(b * 8 + h) * 64) * 64 + e;  // + d*64
    float acc = 0.f;
#pragma unroll
    for (int d = 0; d < 64; ++d) acc += ap[d * 64] * sW[h * 64 + d];
    M2T[((size_t)bn) * 512 + c] = f2bf(acc);
  }
}

// ---------------------------------------------------------------------------
// depthwise 3x3, SAME pad, NHWC (b,128,128,512). 2 channels/thread.
__global__ __launch_bounds__(256)
void dwconv_kernel(const unsigned short* __restrict__ in,
                   const float* __restrict__ w,
                   unsigned short* __restrict__ out, int do_gelu) {
  size_t i = (size_t)blockIdx.x * 256 + threadIdx.x;  // pair index
  int c = (int)(i & 255) * 2;
  size_t p = i >> 8;
  int x = (int)(p & 127);
  int y = (int)((p >> 7) & 127);
  int b = (int)(p >> 14);
  float w0[9], w1[9];
#pragma unroll
  for (int kk = 0; kk < 9; ++kk) { w0[kk] = w[c * 9 + kk]; w1[kk] = w[c * 9 + 9 + kk]; }
  float a0 = 0.f, a1 = 0.f;
#pragma unroll
  for (int ky = 0; ky < 3; ++ky) {
    int yy = y + ky - 1;
    if (yy < 0 || yy > 127) continue;
#pragma unroll
    for (int kx = 0; kx < 3; ++kx) {
      int xx = x + kx - 1;
      if (xx < 0 || xx > 127) continue;
      size_t g = ((((size_t)b * 128 + yy) * 128 + xx) << 9) + c;
      ushort2 u = *(const ushort2*)&in[g];
      a0 += w0[ky * 3 + kx] * bf2f(u.x);
      a1 += w1[ky * 3 + kx] * bf2f(u.y);
    }
  }
  if (do_gelu) {
    a0 = 0.5f * a0 * (1.f + erff(a0 * 0.70710678118654752f));
    a1 = 0.5f * a1 * (1.f + erff(a1 * 0.70710678118654752f));
  }
  unsigned short r[2] = {f2bf(a0), f2bf(a1)};
  *(ushort2*)&out[i * 2] = *(ushort2*)r;
}

// ---------------------------------------------------------------------------
extern "C" void kernel_launch(void* const* d_in, const int* in_sizes, int n_in,
                              void* d_out, int out_size, void* d_ws,
                              size_t ws_size, hipStream_t stream) {
  const float* x    = (const float*)d_in[0];
  const float* illu = (const float*)d_in[1];
  const float* Wq   = (const float*)d_in[2];
  const float* Wk   = (const float*)d_in[3];
  const float* Wv   = (const float*)d_in[4];
  const float* resc = (const float*)d_in[5];
  const float* Wp   = (const float*)d_in[6];
  const float* bp   = (const float*)d_in[7];
  const float* c1w  = (const float*)d_in[8];
  const float* c2w  = (const float*)d_in[9];
  float* out = (float*)d_out;

  char* ws = (char*)d_ws;
  const size_t SZ = (size_t)MROWS * 512 * sizeof(unsigned short);  // 64 MiB
  unsigned short* q_ws = (unsigned short*)(ws);           // later: conv tmp
  unsigned short* k_ws = (unsigned short*)(ws + SZ);      // later: out_p
  unsigned short* v_ws = (unsigned short*)(ws + 2 * SZ);
  unsigned short* x_bf = (unsigned short*)(ws + 3 * SZ);  // later: vg
  unsigned short* WqT = (unsigned short*)(ws + 4 * SZ);
  unsigned short* WkT = WqT + 512 * 512;
  unsigned short* WvT = WkT + 512 * 512;
  unsigned short* WpT = WvT + 512 * 512;
  unsigned short* M2T = WpT + 512 * 512;    // [4][512][512] bf16
  float* S   = (float*)(M2T + 4 * 512 * 512);   // [4][8][64][64]
  float* inv = S + 4 * 8 * 64 * 64;             // [2][4][512]

  transpose512<<<1024, 256, 0, stream>>>(Wq, WqT);
  transpose512<<<1024, 256, 0, stream>>>(Wk, WkT);
  transpose512<<<1024, 256, 0, stream>>>(Wv, WvT);
  transpose512<<<1024, 256, 0, stream>>>(Wp, WpT);
  convert_bf16<<<32768, 256, 0, stream>>>(x, x_bf);
  hipMemsetAsync(S, 0, (size_t)(4 * 8 * 64 * 64 + 2 * 4 * 512) * sizeof(float),
                 stream);

  // projections (bf16 in -> bf16 out)
  gemm_bt<0><<<dim3(512, 4), 256, 0, stream>>>(x_bf, WqT, q_ws, nullptr, nullptr);
  gemm_bt<0><<<dim3(512, 4), 256, 0, stream>>>(x_bf, WkT, k_ws, nullptr, nullptr);
  gemm_bt<0><<<dim3(512, 4), 256, 0, stream>>>(x_bf, WvT, v_ws, nullptr, nullptr);

  // norms + attention scores + softmax
  sumsq_kernel<<<dim3(64, 4, 2), 256, 0, stream>>>(q_ws, k_ws, inv);
  inv_norm_kernel<<<16, 256, 0, stream>>>(inv);
  score_kernel<<<dim3(32, 32), 256, 0, stream>>>(q_ws, k_ws, S);
  softmax_kernel<<<2048, 64, 0, stream>>>(S, inv, resc);

  // fold attention into output projection
  combine_kernel<<<2048, 256, 0, stream>>>(S, WpT, M2T);

  // gated values (x_bf dead after projections -> reuse as vg)
  gate_kernel<<<32768, 256, 0, stream>>>(v_ws, illu, x_bf);

  // positional branch (q_ws/k_ws free after score)
  dwconv_kernel<<<65536, 256, 0, stream>>>(v_ws, c1w, q_ws, 1);
  dwconv_kernel<<<65536, 256, 0, stream>>>(q_ws, c2w, k_ws, 0);

  // out = Vg @ M2T^T + bp + out_p  (fp32 output)
  gemm_bt<1><<<dim3(512, 4), 256, 0, stream>>>(x_bf, M2T, out, bp, k_ws);
}